// Round 4
// baseline (792.203 us; speedup 1.0000x reference)
//
#include <hip/hip_runtime.h>

#define N_NODES 100000
#define N_EDGES 1600000
#define DIM 64
#define NLAYER 4
#define NGRAPH 128
#define BN_EPS 1e-5f
#define AGG_CHUNK 16
#define NCHUNK (N_NODES / AGG_CHUNK)   // 6250

typedef unsigned short ushort_t;
typedef unsigned int uint_t;
typedef unsigned long long ull_t;
typedef __attribute__((ext_vector_type(8))) short short8;
typedef __attribute__((ext_vector_type(4))) float f32x4;

__device__ __forceinline__ ushort_t f2bf(float f) {
    uint_t u = __float_as_uint(f);
    uint_t r = (u + 0x7FFFu + ((u >> 16) & 1u)) >> 16;
    return (ushort_t)r;
}
__device__ __forceinline__ float bf2f(ushort_t u) {
    return __uint_as_float((uint_t)u << 16);
}
__device__ __forceinline__ void bf4_to_f32(const uint2 v, float f[4]) {
    f[0] = __uint_as_float(v.x << 16);
    f[1] = __uint_as_float(v.x & 0xFFFF0000u);
    f[2] = __uint_as_float(v.y << 16);
    f[3] = __uint_as_float(v.y & 0xFFFF0000u);
}

// ---------------- CSR build (r11: de-sharded; rows padded to mult-of-4) -----

__global__ void k_hist(const int* __restrict__ ei, int* __restrict__ cnt,
                       int* __restrict__ rank) {
    int e = blockIdx.x * blockDim.x + threadIdx.x;
    if (e < N_EDGES) {
        int d = ei[N_EDGES + e];
        rank[e] = atomicAdd(&cnt[d], 1);
    }
}

// exclusive scan of ceil4(cnt) -> rowptr4 (16B-aligned csr rows)
__global__ void k_scan1(const int* __restrict__ cnt, int* __restrict__ exc,
                        int* __restrict__ bsums) {
    __shared__ int s[256];
    int i = blockIdx.x * 256 + threadIdx.x;
    int v = (i < N_NODES) ? ((cnt[i] + 3) & ~3) : 0;
    s[threadIdx.x] = v;
    __syncthreads();
    for (int off = 1; off < 256; off <<= 1) {
        int t = (threadIdx.x >= off) ? s[threadIdx.x - off] : 0;
        __syncthreads();
        s[threadIdx.x] += t;
        __syncthreads();
    }
    if (i < N_NODES) exc[i] = s[threadIdx.x] - v;
    if (threadIdx.x == 255) bsums[blockIdx.x] = s[255];
}

__global__ void k_scan2(const int* __restrict__ bsums, int* __restrict__ boffs, int nb) {
    __shared__ int s[512];
    int v = ((int)threadIdx.x < nb) ? bsums[threadIdx.x] : 0;
    s[threadIdx.x] = v;
    __syncthreads();
    for (int off = 1; off < 512; off <<= 1) {
        int t = (threadIdx.x >= off) ? s[threadIdx.x - off] : 0;
        __syncthreads();
        s[threadIdx.x] += t;
        __syncthreads();
    }
    if ((int)threadIdx.x < nb) boffs[threadIdx.x] = s[threadIdx.x] - v;
}

__global__ void k_scan3(int* __restrict__ exc, const int* __restrict__ boffs) {
    int i = blockIdx.x * 256 + threadIdx.x;
    if (i < N_NODES) exc[i] += boffs[blockIdx.x];
}

__global__ void k_fill(const int* __restrict__ ei, const int* __restrict__ rowptr4,
                       const int* __restrict__ rank, int* __restrict__ csr) {
    int e = blockIdx.x * blockDim.x + threadIdx.x;
    if (e < N_EDGES) {
        int d = ei[N_EDGES + e];
        csr[rowptr4[d] + rank[e]] = ei[e];
    }
}

__global__ void k_prep(const int* __restrict__ cnt, const int* __restrict__ batch,
                       float* __restrict__ invdeg, float* __restrict__ invg) {
    int i = blockIdx.x * blockDim.x + threadIdx.x;
    if (i < N_NODES) invdeg[i] = 1.0f / (float)max(cnt[i], 1);
    if (i < NGRAPH) {
        int key = i, lo = 0, hi = N_NODES;
        while (lo < hi) { int m = (lo + hi) >> 1; if (batch[m] < key) lo = m + 1; else hi = m; }
        int a = lo;
        key = i + 1; lo = 0; hi = N_NODES;
        while (lo < hi) { int m = (lo + hi) >> 1; if (batch[m] < key) lo = m + 1; else hi = m; }
        invg[i] = 1.0f / (float)max(lo - a, 1);
    }
}

// x -> bf16 column slices xq[4][N][16]
__global__ void k_xcastq(const float* __restrict__ x, ushort_t* __restrict__ xq) {
    int i = blockIdx.x * blockDim.x + threadIdx.x;   // over N*32 col-pairs
    if (i < N_NODES * 32) {
        const int n = i >> 5, p = i & 31;            // cols 2p, 2p+1
        const float lo = x[(size_t)n * 64 + 2 * p];
        const float hi = x[(size_t)n * 64 + 2 * p + 1];
        const uint_t d = (uint_t)f2bf(lo) | ((uint_t)f2bf(hi) << 16);
        const int q = p >> 3, ci = p & 7;            // slice, dword-in-slice-row
        ((uint_t*)xq)[((size_t)q * N_NODES + n) * 8 + ci] = d;
    }
}

// ---------------- Quarter gather: t_q = agg_mean(h_q) + self_q -------------
// r11 core idea: the gather table sliced to 3.2 MB fits per-XCD L2 (4 MB).
// One dispatch per quarter (grid-wide temporal separation keeps the slice
// resident; r10's full 12.8 MB table was fed by L3 at ~1.85 TB/s random).
// Node-per-slot layout: wave owns 16 nodes; slot s=lane>>2 owns node n0+s,
// its 4 lanes (c4=lane&3) cover the 32B slice row. No cross-lane reduce.
// Index loads 4-batched (dwordx4, rows 16B-aligned via padded CSR) so 4
// row-gathers are in flight per wave; zero LDS -> high occupancy.

__global__ __launch_bounds__(256, 8)
void k_gq(const ushort_t* __restrict__ hq, const int* __restrict__ rowptr4,
          const int* __restrict__ cnt, const int* __restrict__ csr,
          const float* __restrict__ invdeg, ushort_t* __restrict__ tq, int qtr) {
    const int lane = threadIdx.x & 63;
    const int s = lane >> 2;
    const int c4 = lane & 3;
    const int wid = (blockIdx.x << 2) | (threadIdx.x >> 6);
    if (wid >= NCHUNK) return;
    const int n = wid * AGG_CHUNK + s;

    const size_t qoff = (size_t)qtr * N_NODES * 16;
    const ushort_t* __restrict__ hs = hq + qoff;
    ushort_t* __restrict__ ts = (ushort_t*)tq + qoff;

    const int* __restrict__ cp = csr + rowptr4[n];
    const int deg = cnt[n];
    int dmax = deg;
    dmax = max(dmax, __shfl_xor(dmax, 4, 64));
    dmax = max(dmax, __shfl_xor(dmax, 8, 64));
    dmax = max(dmax, __shfl_xor(dmax, 16, 64));
    dmax = max(dmax, __shfl_xor(dmax, 32, 64));

    float acc[4] = {0.f, 0.f, 0.f, 0.f};
    for (int e = 0; e < dmax; e += 4) {
        // padded rows: always in-bounds; garbage entries masked below
        const int i0 = __builtin_nontemporal_load(&cp[e]);
        const int i1 = __builtin_nontemporal_load(&cp[e + 1]);
        const int i2 = __builtin_nontemporal_load(&cp[e + 2]);
        const int i3 = __builtin_nontemporal_load(&cp[e + 3]);
        const int ia[4] = {i0, i1, i2, i3};
#pragma unroll
        for (int k = 0; k < 4; k++) {
            if (e + k < deg) {
                const uint2 v = *(const uint2*)(hs + (size_t)(uint_t)ia[k] * 16 + (c4 << 2));
                float f[4];
                bf4_to_f32(v, f);
                acc[0] += f[0];
                acc[1] += f[1];
                acc[2] += f[2];
                acc[3] += f[3];
            }
        }
    }

    const float idg = invdeg[n];
    const uint2 sv = *(const uint2*)(hs + (size_t)n * 16 + (c4 << 2));
    float sf[4];
    bf4_to_f32(sv, sf);
    const float t0 = fmaf(acc[0], idg, sf[0]);
    const float t1 = fmaf(acc[1], idg, sf[1]);
    const float t2 = fmaf(acc[2], idg, sf[2]);
    const float t3 = fmaf(acc[3], idg, sf[3]);
    const uint_t d0 = (uint_t)f2bf(t0) | ((uint_t)f2bf(t1) << 16);
    const uint_t d1 = (uint_t)f2bf(t2) | ((uint_t)f2bf(t3) << 16);
    uint_t* dst = (uint_t*)(ts + (size_t)n * 16) + (c4 << 1);
    __builtin_nontemporal_store(d0, dst);       // nt: don't evict the h slice
    __builtin_nontemporal_store(d1, dst + 1);
}

// ---------------- Dense MFMA: z = t @ W1 + b1, BN moments -------------------
// A-fragment from slices: k = quad*8+j -> slice quad>>1 (a0) / 2+(quad>>1)
// (a1), within-slice offset (quad&1)*8. Proven mapping [m89/m120].

__global__ __launch_bounds__(256, 4)
void k_mmA(const ushort_t* __restrict__ t, const float* __restrict__ W1,
           const float* __restrict__ b1, float* __restrict__ z,
           float* __restrict__ colsum, float* __restrict__ colsumsq) {
    __shared__ ushort_t wfrag[512 * 8];
    __shared__ float red[128];

    const int w = threadIdx.x >> 6;
    const int lane = threadIdx.x & 63;
    const int wid = __builtin_amdgcn_readfirstlane((blockIdx.x << 2) | w);
    const bool active = wid < NCHUNK;
    const int n0 = (active ? wid : 0) * AGG_CHUNK;

    for (int s = threadIdx.x; s < 512; s += 256) {
        const int hh = s >> 8, c = (s >> 6) & 3, L = s & 63;
        const int kb = hh * 32 + ((L >> 4) * 8);
        const int out = c * 16 + (L & 15);
        uint_t* dst = (uint_t*)&wfrag[s * 8];
#pragma unroll
        for (int j2 = 0; j2 < 4; j2++) {
            const float lo = W1[(kb + 2 * j2) * 64 + out];
            const float hi = W1[(kb + 2 * j2 + 1) * 64 + out];
            dst[j2] = (uint_t)f2bf(lo) | ((uint_t)f2bf(hi) << 16);
        }
    }
    if (threadIdx.x < 128) red[threadIdx.x] = 0.f;
    __syncthreads();

    const int m = lane & 15;
    const int quad = lane >> 4;
    const int node = n0 + m;
    const short8 a0 = *(const short8*)(t +
        ((size_t)((quad >> 1) * N_NODES) + node) * 16 + ((quad & 1) << 3));
    const short8 a1 = *(const short8*)(t +
        ((size_t)(((quad >> 1) + 2) * N_NODES) + node) * 16 + ((quad & 1) << 3));

    float lsum[4], lsq[4];
#pragma unroll
    for (int c = 0; c < 4; c++) {
        const short8 b0 = *(const short8*)&wfrag[(size_t)(c * 64 + lane) * 8];
        const short8 b1f = *(const short8*)&wfrag[(size_t)((4 + c) * 64 + lane) * 8];
        f32x4 D = {0.f, 0.f, 0.f, 0.f};
        D = __builtin_amdgcn_mfma_f32_16x16x32_bf16(a0, b0, D, 0, 0, 0);
        D = __builtin_amdgcn_mfma_f32_16x16x32_bf16(a1, b1f, D, 0, 0, 0);
        const float bv = b1[c * 16 + m];
        float s = 0.f, sq = 0.f;
#pragma unroll
        for (int reg = 0; reg < 4; reg++) {
            const float zv = D[reg] + bv;
            if (active) {
                const int nd = n0 + quad * 4 + reg;
                __builtin_nontemporal_store(zv, &z[(size_t)nd * 64 + c * 16 + m]);
            }
            s += zv;
            sq += zv * zv;
        }
        lsum[c] = s;
        lsq[c] = sq;
    }

    if (active) {
#pragma unroll
        for (int c = 0; c < 4; c++) {
            float s = lsum[c], sq = lsq[c];
            s += __shfl_xor(s, 16, 64);
            s += __shfl_xor(s, 32, 64);
            sq += __shfl_xor(sq, 16, 64);
            sq += __shfl_xor(sq, 32, 64);
            if (quad == 0) {
                atomicAdd(&red[c * 16 + m], s);
                atomicAdd(&red[64 + c * 16 + m], sq);
            }
        }
    }
    __syncthreads();
    if (threadIdx.x < 64) {
        atomicAdd(&colsum[threadIdx.x], red[threadIdx.x]);
        atomicAdd(&colsumsq[threadIdx.x], red[64 + threadIdx.x]);
    }
}

// ---------------- Pass B: BN + ReLU + MFMA GEMV(W2) -> h row-major + slices -

__global__ __launch_bounds__(256, 4)
void k_passB(const float* __restrict__ z, const float* __restrict__ W2,
             const float* __restrict__ b2, const float* __restrict__ colsum,
             const float* __restrict__ colsumsq, const float* __restrict__ gamma,
             const float* __restrict__ beta, ushort_t* __restrict__ hout,
             ushort_t* __restrict__ houtq) {
    __shared__ ushort_t wfrag[512 * 8];
    __shared__ float sscale[64], sshift[64];
    __shared__ float ltile[4][16 * 68];

    const int w = threadIdx.x >> 6;
    const int lane = threadIdx.x & 63;
    const int wid = __builtin_amdgcn_readfirstlane((blockIdx.x << 2) | w);
    const bool active = wid < NCHUNK;
    const int n0 = (active ? wid : 0) * AGG_CHUNK;

    for (int s = threadIdx.x; s < 512; s += 256) {
        const int hh = s >> 8, c = (s >> 6) & 3, L = s & 63;
        const int kb = hh * 32 + ((L >> 4) * 8);
        const int out = c * 16 + (L & 15);
        uint_t* dst = (uint_t*)&wfrag[s * 8];
#pragma unroll
        for (int j2 = 0; j2 < 4; j2++) {
            const float lo = W2[(kb + 2 * j2) * 64 + out];
            const float hi = W2[(kb + 2 * j2 + 1) * 64 + out];
            dst[j2] = (uint_t)f2bf(lo) | ((uint_t)f2bf(hi) << 16);
        }
    }
    if (threadIdx.x < 64) {
        const float invn = 1.0f / (float)N_NODES;
        const float mu = colsum[threadIdx.x] * invn;
        const float var = colsumsq[threadIdx.x] * invn - mu * mu;
        const float sc = gamma[threadIdx.x] * rsqrtf(var + BN_EPS);
        sscale[threadIdx.x] = sc;
        sshift[threadIdx.x] = beta[threadIdx.x] - mu * sc;
    }
    __syncthreads();

    const int m = lane & 15;
    const int quad = lane >> 4;

    const float* zp = z + (size_t)(n0 + m) * 64;
    const f32x4 za = __builtin_nontemporal_load((const f32x4*)(zp + quad * 8));
    const f32x4 zb = __builtin_nontemporal_load((const f32x4*)(zp + quad * 8 + 4));
    const f32x4 zc = __builtin_nontemporal_load((const f32x4*)(zp + 32 + quad * 8));
    const f32x4 zd = __builtin_nontemporal_load((const f32x4*)(zp + 32 + quad * 8 + 4));
    const f32x4 c0 = *(const f32x4*)&sscale[quad * 8];
    const f32x4 c1 = *(const f32x4*)&sscale[quad * 8 + 4];
    const f32x4 c2 = *(const f32x4*)&sscale[32 + quad * 8];
    const f32x4 c3 = *(const f32x4*)&sscale[32 + quad * 8 + 4];
    const f32x4 h0 = *(const f32x4*)&sshift[quad * 8];
    const f32x4 h1v = *(const f32x4*)&sshift[quad * 8 + 4];
    const f32x4 h2v = *(const f32x4*)&sshift[32 + quad * 8];
    const f32x4 h3v = *(const f32x4*)&sshift[32 + quad * 8 + 4];

    float r0[8], r1[8];
#pragma unroll
    for (int j = 0; j < 4; j++) {
        r0[j]     = fmaxf(fmaf(za[j], c0[j], h0[j]), 0.f);
        r0[4 + j] = fmaxf(fmaf(zb[j], c1[j], h1v[j]), 0.f);
        r1[j]     = fmaxf(fmaf(zc[j], c2[j], h2v[j]), 0.f);
        r1[4 + j] = fmaxf(fmaf(zd[j], c3[j], h3v[j]), 0.f);
    }
    union { uint_t u[4]; short8 v; } pa0, pa1;
#pragma unroll
    for (int j2 = 0; j2 < 4; j2++) {
        pa0.u[j2] = (uint_t)f2bf(r0[2 * j2]) | ((uint_t)f2bf(r0[2 * j2 + 1]) << 16);
        pa1.u[j2] = (uint_t)f2bf(r1[2 * j2]) | ((uint_t)f2bf(r1[2 * j2 + 1]) << 16);
    }
    const short8 a0 = pa0.v;
    const short8 a1 = pa1.v;

#pragma unroll
    for (int c = 0; c < 4; c++) {
        const short8 b0 = *(const short8*)&wfrag[(size_t)(c * 64 + lane) * 8];
        const short8 b1f = *(const short8*)&wfrag[(size_t)((4 + c) * 64 + lane) * 8];
        f32x4 D = {0.f, 0.f, 0.f, 0.f};
        D = __builtin_amdgcn_mfma_f32_16x16x32_bf16(a0, b0, D, 0, 0, 0);
        D = __builtin_amdgcn_mfma_f32_16x16x32_bf16(a1, b1f, D, 0, 0, 0);
        const float bv = b2[c * 16 + m];
#pragma unroll
        for (int reg = 0; reg < 4; reg++)
            ltile[w][(quad * 4 + reg) * 68 + c * 16 + m] = D[reg] + bv;
    }

    if (active) {
        const int qs = lane >> 4, ci = lane & 15;
#pragma unroll
        for (int n = 0; n < 16; n++) {
            const float hv = ltile[w][n * 68 + lane];
            const ushort_t b = f2bf(hv);
            hout[(size_t)(n0 + n) * 64 + lane] = b;
            if (houtq)
                houtq[((size_t)qs * N_NODES + (n0 + n)) * 16 + ci] = b;
        }
    }
}

// ---------------- Pools (deferred; linearity) -------------------------------

#define POOL_CHUNK 64

__global__ void k_pool(const ushort_t* __restrict__ h1, const ushort_t* __restrict__ h2,
                       const ushort_t* __restrict__ h3, const ushort_t* __restrict__ h4,
                       const int* __restrict__ batch, float* __restrict__ node_pool,
                       float* __restrict__ gacc) {
    const int lane = threadIdx.x & 63;
    const int wid = (blockIdx.x << 2) | (threadIdx.x >> 6);
    const int n0 = wid * POOL_CHUNK;
    if (n0 >= N_NODES) return;
    const int n1 = min(N_NODES, n0 + POOL_CHUNK);
    int curg = -1;
    float ga = 0.f;
    for (int n = n0; n < n1; n++) {
        const size_t off = (size_t)n * 64 + lane;
        const float v = bf2f(h1[off]) + bf2f(h2[off]) + bf2f(h3[off]) + bf2f(h4[off]);
        __builtin_nontemporal_store(v, &node_pool[off]);
        const int g = batch[n];
        if (g != curg) {
            if (curg >= 0) atomicAdd(&gacc[curg * 64 + lane], ga);
            ga = 0.f;
            curg = g;
        }
        ga += v;
    }
    if (curg >= 0) atomicAdd(&gacc[curg * 64 + lane], ga);
}

__global__ void k_gfinal(const float* __restrict__ gacc, const float* __restrict__ invg,
                         float* __restrict__ gout) {
    int i = blockIdx.x * blockDim.x + threadIdx.x;
    if (i < NGRAPH * 64) gout[i] = gacc[i] * invg[i >> 6];
}

// ---------------- launch ----------------

extern "C" void kernel_launch(void* const* d_in, const int* in_sizes, int n_in,
                              void* d_out, int out_size, void* d_ws, size_t ws_size,
                              hipStream_t stream) {
    (void)in_sizes; (void)n_in; (void)out_size; (void)ws_size;
    const float* x     = (const float*)d_in[0];
    const int*   ei    = (const int*)d_in[1];
    const int*   batch = (const int*)d_in[2];
    const float* W1    = (const float*)d_in[3];
    const float* b1    = (const float*)d_in[4];
    const float* gamma = (const float*)d_in[5];
    const float* beta  = (const float*)d_in[6];
    const float* W2    = (const float*)d_in[7];
    const float* b2    = (const float*)d_in[8];
    float* out = (float*)d_out;  // [N*64] node_pool, then [G*64] g_pool

    // element offsets (4B units)
    size_t o = 0;
    size_t o_cnt     = o; o += N_NODES;
    size_t o_colsum  = o; o += (size_t)NLAYER * 64;
    size_t o_colsq   = o; o += (size_t)NLAYER * 64;
    size_t o_gacc    = o; o += (size_t)NGRAPH * 64;
    size_t zero_elems = o;                              // ~110K elems
    size_t o_rowptr  = o; o += N_NODES;
    size_t o_bsums   = o; o += 512;
    size_t o_boffs   = o; o += 512;
    size_t o_invdeg  = o; o += N_NODES;
    size_t o_invg    = o; o += NGRAPH;
    size_t o_rank    = o; o += N_EDGES;
    size_t o_csr     = o; o += N_EDGES + 3 * N_NODES + 64;  // padded rows + tail
    size_t o_z       = o; o += (size_t)N_NODES * 64;        // fp32
    size_t o_t       = o; o += (size_t)N_NODES * 32;        // t slices bf16
    size_t o_sA      = o; o += (size_t)N_NODES * 32;        // h slices bf16 (ping)
    size_t o_sB      = o; o += (size_t)N_NODES * 32;        // h slices bf16 (pong)
    size_t o_h0      = o; o += (size_t)N_NODES * 32;        // h row-major per layer
    size_t o_h1      = o; o += (size_t)N_NODES * 32;
    size_t o_h2      = o; o += (size_t)N_NODES * 32;
    size_t o_h3      = o; o += (size_t)N_NODES * 32;

    int*   wsi = (int*)d_ws;
    float* wsf = (float*)d_ws;
    int*      cnt    = wsi + o_cnt;
    float*    colsum = wsf + o_colsum;
    float*    colsq  = wsf + o_colsq;
    float*    gacc   = wsf + o_gacc;
    int*      rowptr = wsi + o_rowptr;
    int*      bsums  = wsi + o_bsums;
    int*      boffs  = wsi + o_boffs;
    float*    invdeg = wsf + o_invdeg;
    float*    invg   = wsf + o_invg;
    int*      rank   = wsi + o_rank;
    int*      csr    = wsi + o_csr;
    float*    zbuf   = wsf + o_z;
    ushort_t* tbuf   = (ushort_t*)(wsi + o_t);
    ushort_t* sA     = (ushort_t*)(wsi + o_sA);
    ushort_t* sB     = (ushort_t*)(wsi + o_sB);
    ushort_t* hrm[NLAYER] = {(ushort_t*)(wsi + o_h0), (ushort_t*)(wsi + o_h1),
                             (ushort_t*)(wsi + o_h2), (ushort_t*)(wsi + o_h3)};

    hipMemsetAsync(d_ws, 0, zero_elems * 4, stream);

    const int eb = (N_EDGES + 255) / 256;
    const int nb = (N_NODES + 255) / 256;  // 391 <= 512

    k_hist<<<eb, 256, 0, stream>>>(ei, cnt, rank);
    k_xcastq<<<(N_NODES * 32 + 255) / 256, 256, 0, stream>>>(x, sA);
    k_scan1<<<nb, 256, 0, stream>>>(cnt, rowptr, bsums);
    k_scan2<<<1, 512, 0, stream>>>(bsums, boffs, nb);
    k_scan3<<<nb, 256, 0, stream>>>(rowptr, boffs);
    k_prep<<<nb, 256, 0, stream>>>(cnt, batch, invdeg, invg);
    k_fill<<<eb, 256, 0, stream>>>(ei, rowptr, rank, csr);

    const int gridC = (NCHUNK + 3) / 4;  // 1563
    const ushort_t* sin[NLAYER] = {sA, sB, sA, sB};
    ushort_t*       sout[NLAYER] = {sB, sA, sB, nullptr};
    for (int l = 0; l < NLAYER; l++) {
        for (int qq = 0; qq < 4; qq++)
            k_gq<<<gridC, 256, 0, stream>>>(sin[l], rowptr, cnt, csr, invdeg,
                                            tbuf, qq);
        k_mmA<<<gridC, 256, 0, stream>>>(tbuf, W1 + l * 4096, b1 + l * 64,
                                         zbuf, colsum + l * 64, colsq + l * 64);
        k_passB<<<gridC, 256, 0, stream>>>(zbuf, W2 + l * 4096, b2 + l * 64,
                                           colsum + l * 64, colsq + l * 64,
                                           gamma + l * 64, beta + l * 64,
                                           hrm[l], sout[l]);
    }
    const int gridP = (N_NODES + POOL_CHUNK * 4 - 1) / (POOL_CHUNK * 4);
    k_pool<<<gridP, 256, 0, stream>>>(hrm[0], hrm[1], hrm[2], hrm[3],
                                      batch, out, gacc);
    k_gfinal<<<32, 256, 0, stream>>>(gacc, invg, out + (size_t)N_NODES * 64);
}

// Round 6
// 575.832 us; speedup vs baseline: 1.3758x; 1.3758x over previous
//
#include <hip/hip_runtime.h>

#define N_NODES 100000
#define N_EDGES 1600000
#define DIM 64
#define NLAYER 4
#define NGRAPH 128
#define BN_EPS 1e-5f
#define NSHARD 16
#define AGG_CHUNK 16
#define NCHUNK (N_NODES / AGG_CHUNK)   // 6250

typedef unsigned short ushort_t;
typedef unsigned int uint_t;
typedef __attribute__((ext_vector_type(8))) short short8;
typedef __attribute__((ext_vector_type(4))) float f32x4;
typedef __attribute__((ext_vector_type(4))) uint_t uintx4;

__device__ __forceinline__ ushort_t f2bf(float f) {
    uint_t u = __float_as_uint(f);
    uint_t r = (u + 0x7FFFu + ((u >> 16) & 1u)) >> 16;
    return (ushort_t)r;
}
__device__ __forceinline__ float bf2f(ushort_t u) {
    return __uint_as_float((uint_t)u << 16);
}
__device__ __forceinline__ void bf8_to_f32(const uint4 v, float f[8]) {
    f[0] = __uint_as_float(v.x << 16);
    f[1] = __uint_as_float(v.x & 0xFFFF0000u);
    f[2] = __uint_as_float(v.y << 16);
    f[3] = __uint_as_float(v.y & 0xFFFF0000u);
    f[4] = __uint_as_float(v.z << 16);
    f[5] = __uint_as_float(v.z & 0xFFFF0000u);
    f[6] = __uint_as_float(v.w << 16);
    f[7] = __uint_as_float(v.w & 0xFFFF0000u);
}

// ---------------- CSR build (r10: sharded hist — r11 proved de-sharded
// atomic-return contention costs ~55 us) ----------------

__global__ void k_hist(const int* __restrict__ ei, int* __restrict__ cntS,
                       int* __restrict__ rank) {
    int e = blockIdx.x * blockDim.x + threadIdx.x;
    if (e < N_EDGES) {
        int d = ei[N_EDGES + e];
        int s = blockIdx.x & (NSHARD - 1);
        rank[e] = atomicAdd(&cntS[s * N_NODES + d], 1);
    }
}

__global__ void k_sumsh(int* __restrict__ cntS, int* __restrict__ cnt) {
    int i = blockIdx.x * blockDim.x + threadIdx.x;
    if (i < N_NODES) {
        int run = 0;
#pragma unroll
        for (int s = 0; s < NSHARD; s++) {
            int c = cntS[s * N_NODES + i];
            cntS[s * N_NODES + i] = run;
            run += c;
        }
        cnt[i] = run;
    }
}

__global__ void k_scan1(const int* __restrict__ cnt, int* __restrict__ exc,
                        int* __restrict__ bsums) {
    __shared__ int s[256];
    int i = blockIdx.x * 256 + threadIdx.x;
    int v = (i < N_NODES) ? cnt[i] : 0;
    s[threadIdx.x] = v;
    __syncthreads();
    for (int off = 1; off < 256; off <<= 1) {
        int t = (threadIdx.x >= off) ? s[threadIdx.x - off] : 0;
        __syncthreads();
        s[threadIdx.x] += t;
        __syncthreads();
    }
    if (i < N_NODES) exc[i] = s[threadIdx.x] - v;
    if (threadIdx.x == 255) bsums[blockIdx.x] = s[255];
}

__global__ void k_scan2(const int* __restrict__ bsums, int* __restrict__ boffs, int nb) {
    __shared__ int s[512];
    int v = ((int)threadIdx.x < nb) ? bsums[threadIdx.x] : 0;
    s[threadIdx.x] = v;
    __syncthreads();
    for (int off = 1; off < 512; off <<= 1) {
        int t = (threadIdx.x >= off) ? s[threadIdx.x - off] : 0;
        __syncthreads();
        s[threadIdx.x] += t;
        __syncthreads();
    }
    if ((int)threadIdx.x < nb) boffs[threadIdx.x] = s[threadIdx.x] - v;
}

// scan3 + prep fused (same grid; prep is independent elementwise work)
__global__ void k_scan3(int* __restrict__ exc, const int* __restrict__ boffs,
                        const int* __restrict__ cnt, const int* __restrict__ batch,
                        float* __restrict__ invdeg, float* __restrict__ invg) {
    int i = blockIdx.x * 256 + threadIdx.x;
    if (i < N_NODES) {
        exc[i] += boffs[blockIdx.x];
        invdeg[i] = 1.0f / (float)max(cnt[i], 1);
    }
    if (i < NGRAPH) {
        int key = i, lo = 0, hi = N_NODES;
        while (lo < hi) { int m = (lo + hi) >> 1; if (batch[m] < key) lo = m + 1; else hi = m; }
        int a = lo;
        key = i + 1; lo = 0; hi = N_NODES;
        while (lo < hi) { int m = (lo + hi) >> 1; if (batch[m] < key) lo = m + 1; else hi = m; }
        invg[i] = 1.0f / (float)max(lo - a, 1);
    }
}

__global__ void k_fill(const int* __restrict__ ei, const int* __restrict__ rowptr,
                       const int* __restrict__ cntS, const int* __restrict__ rank,
                       int* __restrict__ csr) {
    int e = blockIdx.x * blockDim.x + threadIdx.x;
    if (e < N_EDGES) {
        int d = ei[N_EDGES + e];
        int s = blockIdx.x & (NSHARD - 1);
        csr[rowptr[d] + cntS[s * N_NODES + d] + rank[e]] = ei[e];
    }
}

__global__ void k_xcast(const float* __restrict__ x, ushort_t* __restrict__ xh) {
    int i = blockIdx.x * blockDim.x + threadIdx.x;
    if (i < N_NODES * 16) {
        const float4 v = ((const float4*)x)[i];
        ushort4 u;
        u.x = f2bf(v.x); u.y = f2bf(v.y); u.z = f2bf(v.z); u.w = f2bf(v.w);
        ((ushort4*)xh)[i] = u;
    }
}

// One masked group of 8 edges; bf16 rows, octet layout (q=lane>>3 edge slot,
// r=lane&7 column octet). 1 idx load + 1 dwordx4 gather per 8 edges.
__device__ __forceinline__ void grp8b(const ushort_t* __restrict__ h,
                                      const int* __restrict__ cp,
                                      int e, int deg, int q, int r,
                                      float acc[8]) {
    const int last = deg - 1;
    const int e0 = e + q;
    int i0 = cp[min(e0, last)];
    float m0 = (e0 < deg) ? 1.f : 0.f;
    const uint4 v = *(const uint4*)(h + (size_t)i0 * 64 + r * 8);
    float f[8];
    bf8_to_f32(v, f);
#pragma unroll
    for (int j = 0; j < 8; j++) acc[j] = fmaf(f[j], m0, acc[j]);
}

// ---------------- Layer pass A: gather + t-store + MFMA(W1) + BN moments ----
// r13: r7/r10 gather structure untouched (proven at the ~2.6 TB/s supply
// ceiling; r8/r9/r11 all failed to beat it). Change vs r10: persist t (bf16,
// 12.8 MB, coalesced from the already-staged smt tile) instead of z (fp32,
// 25.6 MB). BN stats still computed here from MFMA registers; passB
// recomputes z = t@W1+b1 bitwise-identically (same bf16 frags).

__global__ __launch_bounds__(256, 4)
void k_passA(const ushort_t* __restrict__ h, const float* __restrict__ W1,
             const float* __restrict__ b1,
             const int* __restrict__ rowptr, const int* __restrict__ cnt,
             const int* __restrict__ csr, const float* __restrict__ invdeg,
             ushort_t* __restrict__ tglob, float* __restrict__ colsum,
             float* __restrict__ colsumsq) {
    __shared__ ushort_t wfrag[512 * 8];     // [(hh*4+c)*64+lane] -> 8 bf16
    __shared__ uint_t smt[4][16 * 36];      // per-wave t tile, row stride 36 dw
    __shared__ float red[128];              // block partial colsum / colsumsq

    const int w = threadIdx.x >> 6;
    const int lane = threadIdx.x & 63;
    const int q = lane >> 3;
    const int r = lane & 7;
    const int wid = __builtin_amdgcn_readfirstlane((blockIdx.x << 2) | w);
    const bool active = wid < NCHUNK;
    const int n0 = (active ? wid : 0) * AGG_CHUNK;

    // build W1 bf16 B-fragments: slot (hh,c,L): j -> W1[hh*32+(L>>4)*8+j][c*16+(L&15)]
    for (int s = threadIdx.x; s < 512; s += 256) {
        const int hh = s >> 8, c = (s >> 6) & 3, L = s & 63;
        const int kb = hh * 32 + ((L >> 4) * 8);
        const int out = c * 16 + (L & 15);
        uint_t* dst = (uint_t*)&wfrag[s * 8];
#pragma unroll
        for (int j2 = 0; j2 < 4; j2++) {
            const float lo = W1[(kb + 2 * j2) * 64 + out];
            const float hi = W1[(kb + 2 * j2 + 1) * 64 + out];
            dst[j2] = (uint_t)f2bf(lo) | ((uint_t)f2bf(hi) << 16);
        }
    }
    if (threadIdx.x < 128) red[threadIdx.x] = 0.f;
    __syncthreads();

    // gather 16 nodes (8 pairs), stage t rows as bf16 into smt
    if (active) {
        for (int pp = 0; pp < AGG_CHUNK; pp += 2) {
            const int n = n0 + pp;
            const int sa = rowptr[n],     da = cnt[n];
            const int sb = rowptr[n + 1], db = cnt[n + 1];
            const float idga = invdeg[n], idgb = invdeg[n + 1];
            const int* __restrict__ ca = csr + sa;
            const int* __restrict__ cb = csr + sb;

            float aa[8] = {0,0,0,0,0,0,0,0};
            float ab[8] = {0,0,0,0,0,0,0,0};
            const int mm = min(da, db);
            int e = 0;
            for (; e < mm; e += 8) {
                grp8b(h, ca, e, da, q, r, aa);
                grp8b(h, cb, e, db, q, r, ab);
            }
            for (; e < da; e += 8) grp8b(h, ca, e, da, q, r, aa);
            for (; e < db; e += 8) grp8b(h, cb, e, db, q, r, ab);

#pragma unroll
            for (int j = 0; j < 8; j++) {
                aa[j] += __shfl_xor(aa[j], 8, 64);
                aa[j] += __shfl_xor(aa[j], 16, 64);
                aa[j] += __shfl_xor(aa[j], 32, 64);
                ab[j] += __shfl_xor(ab[j], 8, 64);
                ab[j] += __shfl_xor(ab[j], 16, 64);
                ab[j] += __shfl_xor(ab[j], 32, 64);
            }

            const uint4 sva = *(const uint4*)(h + (size_t)n * 64 + r * 8);
            const uint4 svb = *(const uint4*)(h + (size_t)(n + 1) * 64 + r * 8);
            float sa8[8], sb8[8];
            bf8_to_f32(sva, sa8);
            bf8_to_f32(svb, sb8);
            float ta[8], tb[8];
#pragma unroll
            for (int j = 0; j < 8; j++) {
                ta[j] = fmaf(aa[j], idga, sa8[j]);
                tb[j] = fmaf(ab[j], idgb, sb8[j]);
            }

            if (q < 2) {   // lanes q==0 stage node pp, q==1 stage node pp+1
                const int row = pp + q;
                uint_t* dst = &smt[w][row * 36 + r * 4];
#pragma unroll
                for (int j2 = 0; j2 < 4; j2++) {
                    const float lo = q ? tb[2 * j2]     : ta[2 * j2];
                    const float hi = q ? tb[2 * j2 + 1] : ta[2 * j2 + 1];
                    dst[j2] = (uint_t)f2bf(lo) | ((uint_t)f2bf(hi) << 16);
                }
            }
        }
    }

    // persist t (bf16, coalesced): lane L copies 8 dwords of row L>>2
    if (active) {
        const int rr = lane >> 2, c4 = lane & 3;
        const uint_t* src = &smt[w][rr * 36 + c4 * 8];
        uintx4 v0, v1;
#pragma unroll
        for (int j = 0; j < 4; j++) { v0[j] = src[j]; v1[j] = src[4 + j]; }
        uintx4* dst = (uintx4*)((uint_t*)tglob + (size_t)(n0 + rr) * 32) + c4 * 2;
        __builtin_nontemporal_store(v0, dst);
        __builtin_nontemporal_store(v1, dst + 1);
    }

    // MFMA: A = t tile (m=lane&15, k=quad*8+j), two K-halves
    const int m = lane & 15;
    const int quad = lane >> 4;
    const short8 a0 = *(const short8*)&smt[w][m * 36 + quad * 4];
    const short8 a1 = *(const short8*)&smt[w][m * 36 + 16 + quad * 4];

    float lsum[4], lsq[4];
#pragma unroll
    for (int c = 0; c < 4; c++) {
        const short8 b0 = *(const short8*)&wfrag[(size_t)(c * 64 + lane) * 8];
        const short8 b1f = *(const short8*)&wfrag[(size_t)((4 + c) * 64 + lane) * 8];
        f32x4 D = {0.f, 0.f, 0.f, 0.f};
        D = __builtin_amdgcn_mfma_f32_16x16x32_bf16(a0, b0, D, 0, 0, 0);
        D = __builtin_amdgcn_mfma_f32_16x16x32_bf16(a1, b1f, D, 0, 0, 0);
        const float bv = b1[c * 16 + m];
        float s = 0.f, sq = 0.f;
#pragma unroll
        for (int reg = 0; reg < 4; reg++) {
            const float zv = D[reg] + bv;
            s += zv;
            sq += zv * zv;
        }
        lsum[c] = s;
        lsq[c] = sq;
    }

    if (active) {
#pragma unroll
        for (int c = 0; c < 4; c++) {
            float s = lsum[c], sq = lsq[c];
            s += __shfl_xor(s, 16, 64);
            s += __shfl_xor(s, 32, 64);
            sq += __shfl_xor(sq, 16, 64);
            sq += __shfl_xor(sq, 32, 64);
            if (quad == 0) {
                atomicAdd(&red[c * 16 + m], s);
                atomicAdd(&red[64 + c * 16 + m], sq);
            }
        }
    }
    __syncthreads();
    if (threadIdx.x < 64) {
        atomicAdd(&colsum[threadIdx.x], red[threadIdx.x]);
        atomicAdd(&colsumsq[threadIdx.x], red[64 + threadIdx.x]);
    }
}

// ---------------- Layer pass B: z=t@W1+b1 (recompute), BN+ReLU, @W2 -> h ----
// Reads t bf16 (12.8 MB vs r10's 25.6 MB z). MFMA1 reproduces passA's z
// bitwise (same bf16 fragments); BN applied in D-layout; transpose through
// wave-private ltile; MFMA2 with W2; bf16 h out.

__global__ __launch_bounds__(256, 4)
void k_passB(const ushort_t* __restrict__ t, const float* __restrict__ W1,
             const float* __restrict__ b1, const float* __restrict__ W2,
             const float* __restrict__ b2, const float* __restrict__ colsum,
             const float* __restrict__ colsumsq, const float* __restrict__ gamma,
             const float* __restrict__ beta, ushort_t* __restrict__ hout) {
    __shared__ ushort_t wf1[512 * 8];
    __shared__ ushort_t wf2[512 * 8];
    __shared__ float sscale[64], sshift[64];
    __shared__ float ltile[4][16 * 68];

    const int w = threadIdx.x >> 6;
    const int lane = threadIdx.x & 63;
    const int wid = __builtin_amdgcn_readfirstlane((blockIdx.x << 2) | w);
    const bool active = wid < NCHUNK;
    const int n0 = (active ? wid : 0) * AGG_CHUNK;

    for (int s = threadIdx.x; s < 1024; s += 256) {
        const int which = s >> 9, t2 = s & 511;
        const int hh = t2 >> 8, c = (t2 >> 6) & 3, L = t2 & 63;
        const int kb = hh * 32 + ((L >> 4) * 8);
        const int out = c * 16 + (L & 15);
        const float* W = which ? W2 : W1;
        uint_t* dst = (uint_t*)&(which ? wf2 : wf1)[t2 * 8];
#pragma unroll
        for (int j2 = 0; j2 < 4; j2++) {
            const float lo = W[(kb + 2 * j2) * 64 + out];
            const float hi = W[(kb + 2 * j2 + 1) * 64 + out];
            dst[j2] = (uint_t)f2bf(lo) | ((uint_t)f2bf(hi) << 16);
        }
    }
    if (threadIdx.x < 64) {
        const float invn = 1.0f / (float)N_NODES;
        const float mu = colsum[threadIdx.x] * invn;
        const float var = colsumsq[threadIdx.x] * invn - mu * mu;
        const float sc = gamma[threadIdx.x] * rsqrtf(var + BN_EPS);
        sscale[threadIdx.x] = sc;
        sshift[threadIdx.x] = beta[threadIdx.x] - mu * sc;
    }
    __syncthreads();

    const int m = lane & 15;
    const int quad = lane >> 4;

    // A-fragment straight from t rows (row-major bf16)
    const ushort_t* tp = t + (size_t)(n0 + m) * 64;
    const short8 a0 = __builtin_nontemporal_load((const short8*)(tp + quad * 8));
    const short8 a1 = __builtin_nontemporal_load((const short8*)(tp + 32 + quad * 8));

    // MFMA1: z tile, BN+ReLU in D-layout, stash fp32 into ltile
#pragma unroll
    for (int c = 0; c < 4; c++) {
        const short8 b0 = *(const short8*)&wf1[(size_t)(c * 64 + lane) * 8];
        const short8 b1f = *(const short8*)&wf1[(size_t)((4 + c) * 64 + lane) * 8];
        f32x4 D = {0.f, 0.f, 0.f, 0.f};
        D = __builtin_amdgcn_mfma_f32_16x16x32_bf16(a0, b0, D, 0, 0, 0);
        D = __builtin_amdgcn_mfma_f32_16x16x32_bf16(a1, b1f, D, 0, 0, 0);
        const int col = c * 16 + m;
        const float bv = b1[col];
        const float sc = sscale[col], sh = sshift[col];
#pragma unroll
        for (int reg = 0; reg < 4; reg++) {
            const float zv = D[reg] + bv;
            ltile[w][(quad * 4 + reg) * 68 + col] = fmaxf(fmaf(zv, sc, sh), 0.f);
        }
    }

    // transpose read: lane m rows, cols quad*8.. (wave-private, wave-sync)
    const float* lr = &ltile[w][m * 68];
    float r0[8], r1[8];
#pragma unroll
    for (int j = 0; j < 8; j++) {
        r0[j] = lr[quad * 8 + j];
        r1[j] = lr[32 + quad * 8 + j];
    }
    union { uint_t u[4]; short8 v; } pa0, pa1;
#pragma unroll
    for (int j2 = 0; j2 < 4; j2++) {
        pa0.u[j2] = (uint_t)f2bf(r0[2 * j2]) | ((uint_t)f2bf(r0[2 * j2 + 1]) << 16);
        pa1.u[j2] = (uint_t)f2bf(r1[2 * j2]) | ((uint_t)f2bf(r1[2 * j2 + 1]) << 16);
    }
    const short8 c0 = pa0.v;
    const short8 c1 = pa1.v;

    // MFMA2: h tile, back into ltile (all lanes re-read before overwrite:
    // wave-synchronous instruction stream makes this safe)
#pragma unroll
    for (int c = 0; c < 4; c++) {
        const short8 b0 = *(const short8*)&wf2[(size_t)(c * 64 + lane) * 8];
        const short8 b1f = *(const short8*)&wf2[(size_t)((4 + c) * 64 + lane) * 8];
        f32x4 D = {0.f, 0.f, 0.f, 0.f};
        D = __builtin_amdgcn_mfma_f32_16x16x32_bf16(c0, b0, D, 0, 0, 0);
        D = __builtin_amdgcn_mfma_f32_16x16x32_bf16(c1, b1f, D, 0, 0, 0);
        const float bv = b2[c * 16 + m];
#pragma unroll
        for (int reg = 0; reg < 4; reg++)
            ltile[w][(quad * 4 + reg) * 68 + c * 16 + m] = D[reg] + bv;
    }

    if (active) {
#pragma unroll
        for (int n = 0; n < 16; n++) {
            const float hv = ltile[w][n * 68 + lane];
            hout[(size_t)(n0 + n) * 64 + lane] = f2bf(hv);
        }
    }
}

// ---------------- Pools (deferred; linearity) -------------------------------

#define POOL_CHUNK 64

__global__ void k_pool(const ushort_t* __restrict__ h1, const ushort_t* __restrict__ h2,
                       const ushort_t* __restrict__ h3, const ushort_t* __restrict__ h4,
                       const int* __restrict__ batch, float* __restrict__ node_pool,
                       float* __restrict__ gacc) {
    const int lane = threadIdx.x & 63;
    const int wid = (blockIdx.x << 2) | (threadIdx.x >> 6);
    const int n0 = wid * POOL_CHUNK;
    if (n0 >= N_NODES) return;
    const int n1 = min(N_NODES, n0 + POOL_CHUNK);
    int curg = -1;
    float ga = 0.f;
    for (int n = n0; n < n1; n++) {
        const size_t off = (size_t)n * 64 + lane;
        const float v = bf2f(h1[off]) + bf2f(h2[off]) + bf2f(h3[off]) + bf2f(h4[off]);
        __builtin_nontemporal_store(v, &node_pool[off]);
        const int g = batch[n];
        if (g != curg) {
            if (curg >= 0) atomicAdd(&gacc[curg * 64 + lane], ga);
            ga = 0.f;
            curg = g;
        }
        ga += v;
    }
    if (curg >= 0) atomicAdd(&gacc[curg * 64 + lane], ga);
}

__global__ void k_gfinal(const float* __restrict__ gacc, const float* __restrict__ invg,
                         float* __restrict__ gout) {
    int i = blockIdx.x * blockDim.x + threadIdx.x;
    if (i < NGRAPH * 64) gout[i] = gacc[i] * invg[i >> 6];
}

// ---------------- launch ----------------

extern "C" void kernel_launch(void* const* d_in, const int* in_sizes, int n_in,
                              void* d_out, int out_size, void* d_ws, size_t ws_size,
                              hipStream_t stream) {
    (void)in_sizes; (void)n_in; (void)out_size; (void)ws_size;
    const float* x     = (const float*)d_in[0];
    const int*   ei    = (const int*)d_in[1];
    const int*   batch = (const int*)d_in[2];
    const float* W1    = (const float*)d_in[3];
    const float* b1    = (const float*)d_in[4];
    const float* gamma = (const float*)d_in[5];
    const float* beta  = (const float*)d_in[6];
    const float* W2    = (const float*)d_in[7];
    const float* b2    = (const float*)d_in[8];
    float* out = (float*)d_out;  // [N*64] node_pool, then [G*64] g_pool

    // element offsets (4B units)
    size_t o = 0;
    size_t o_cntS    = o; o += (size_t)NSHARD * N_NODES;
    size_t o_colsum  = o; o += (size_t)NLAYER * 64;
    size_t o_colsq   = o; o += (size_t)NLAYER * 64;
    size_t o_gacc    = o; o += (size_t)NGRAPH * 64;
    size_t zero_elems = o;
    size_t o_cnt     = o; o += N_NODES;
    size_t o_rowptr  = o; o += N_NODES;
    size_t o_bsums   = o; o += 512;
    size_t o_boffs   = o; o += 512;
    size_t o_invdeg  = o; o += N_NODES;
    size_t o_invg    = o; o += NGRAPH;
    size_t o_rank    = o; o += N_EDGES;
    size_t o_csr     = o; o += N_EDGES;
    size_t o_t       = o; o += (size_t)N_NODES * 32;   // t, bf16 (N*64 ushorts)
    size_t o_h0      = o; o += (size_t)N_NODES * 32;   // per-layer h, bf16
    size_t o_h1      = o; o += (size_t)N_NODES * 32;
    size_t o_h2      = o; o += (size_t)N_NODES * 32;
    size_t o_xh      = o; o += (size_t)N_NODES * 32;   // x bf16; reused as h4

    int*   wsi = (int*)d_ws;
    float* wsf = (float*)d_ws;
    int*      cntS   = wsi + o_cntS;
    float*    colsum = wsf + o_colsum;
    float*    colsq  = wsf + o_colsq;
    float*    gacc   = wsf + o_gacc;
    int*      cnt    = wsi + o_cnt;
    int*      rowptr = wsi + o_rowptr;
    int*      bsums  = wsi + o_bsums;
    int*      boffs  = wsi + o_boffs;
    float*    invdeg = wsf + o_invdeg;
    float*    invg   = wsf + o_invg;
    int*      rank   = wsi + o_rank;
    int*      csr    = wsi + o_csr;
    ushort_t* tbuf   = (ushort_t*)(wsi + o_t);
    ushort_t* hb0    = (ushort_t*)(wsi + o_h0);
    ushort_t* hb1    = (ushort_t*)(wsi + o_h1);
    ushort_t* hb2    = (ushort_t*)(wsi + o_h2);
    ushort_t* xh     = (ushort_t*)(wsi + o_xh);   // layer-0 input; layer-3 output

    hipMemsetAsync(d_ws, 0, zero_elems * 4, stream);

    const int eb = (N_EDGES + 255) / 256;
    const int nb = (N_NODES + 255) / 256;  // 391 <= 512

    k_hist<<<eb, 256, 0, stream>>>(ei, cntS, rank);
    k_xcast<<<(N_NODES * 16 + 255) / 256, 256, 0, stream>>>(x, xh);
    k_sumsh<<<nb, 256, 0, stream>>>(cntS, cnt);
    k_scan1<<<nb, 256, 0, stream>>>(cnt, rowptr, bsums);
    k_scan2<<<1, 512, 0, stream>>>(bsums, boffs, nb);
    k_scan3<<<nb, 256, 0, stream>>>(rowptr, boffs, cnt, batch, invdeg, invg);
    k_fill<<<eb, 256, 0, stream>>>(ei, rowptr, cntS, rank, csr);

    const ushort_t* hin[NLAYER]  = {xh,  hb0, hb1, hb2};
    ushort_t*       hoz[NLAYER]  = {hb0, hb1, hb2, xh};   // layer-3 out aliases xh

    const int gridA = (NCHUNK + 3) / 4;  // 1563
    for (int l = 0; l < NLAYER; l++) {
        k_passA<<<gridA, 256, 0, stream>>>(hin[l], W1 + l * 4096, b1 + l * 64,
                                           rowptr, cnt, csr, invdeg,
                                           tbuf, colsum + l * 64, colsq + l * 64);
        k_passB<<<gridA, 256, 0, stream>>>(tbuf, W1 + l * 4096, b1 + l * 64,
                                           W2 + l * 4096, b2 + l * 64,
                                           colsum + l * 64, colsq + l * 64,
                                           gamma + l * 64, beta + l * 64, hoz[l]);
    }
    const int gridP = (N_NODES + POOL_CHUNK * 4 - 1) / (POOL_CHUNK * 4);
    k_pool<<<gridP, 256, 0, stream>>>(hb0, hb1, hb2, xh, batch, out, gacc);
    k_gfinal<<<32, 256, 0, stream>>>(gacc, invg, out + (size_t)N_NODES * 64);
}

// Round 7
// 560.324 us; speedup vs baseline: 1.4138x; 1.0277x over previous
//
#include <hip/hip_runtime.h>

#define N_NODES 100000
#define N_EDGES 1600000
#define DIM 64
#define NLAYER 4
#define NGRAPH 128
#define BN_EPS 1e-5f
#define NSHARD 16
#define AGG_CHUNK 16
#define NCHUNK (N_NODES / AGG_CHUNK)   // 6250

typedef unsigned short ushort_t;
typedef unsigned int uint_t;
typedef __attribute__((ext_vector_type(8))) short short8;
typedef __attribute__((ext_vector_type(4))) float f32x4;
typedef __attribute__((ext_vector_type(4))) uint_t uintx4;

__device__ __forceinline__ ushort_t f2bf(float f) {
    uint_t u = __float_as_uint(f);
    uint_t r = (u + 0x7FFFu + ((u >> 16) & 1u)) >> 16;
    return (ushort_t)r;
}
__device__ __forceinline__ float bf2f(ushort_t u) {
    return __uint_as_float((uint_t)u << 16);
}
__device__ __forceinline__ void bf8_to_f32(const uint4 v, float f[8]) {
    f[0] = __uint_as_float(v.x << 16);
    f[1] = __uint_as_float(v.x & 0xFFFF0000u);
    f[2] = __uint_as_float(v.y << 16);
    f[3] = __uint_as_float(v.y & 0xFFFF0000u);
    f[4] = __uint_as_float(v.z << 16);
    f[5] = __uint_as_float(v.z & 0xFFFF0000u);
    f[6] = __uint_as_float(v.w << 16);
    f[7] = __uint_as_float(v.w & 0xFFFF0000u);
}

// ---------------- CSR build (sharded hist; r11 proved de-sharded returning
// atomics cost ~55 us via cross-XCD line ping-pong; s=block&15 keeps shard
// lines XCD-private under round-robin dispatch) ----------------

__global__ void k_hist(const int* __restrict__ ei, int* __restrict__ cntS,
                       int* __restrict__ rank) {
    int e = blockIdx.x * blockDim.x + threadIdx.x;
    if (e < N_EDGES) {
        int d = ei[N_EDGES + e];
        int s = blockIdx.x & (NSHARD - 1);
        rank[e] = atomicAdd(&cntS[s * N_NODES + d], 1);
    }
}

// r14: sumsh + scan1 fused (identical i-mapping): per-node shard totals ->
// cnt, plus block-local exclusive scan -> exc, bsums.
__global__ void k_sumscan(int* __restrict__ cntS, int* __restrict__ cnt,
                          int* __restrict__ exc, int* __restrict__ bsums) {
    __shared__ int s[256];
    int i = blockIdx.x * 256 + threadIdx.x;
    int run = 0;
    if (i < N_NODES) {
#pragma unroll
        for (int sh = 0; sh < NSHARD; sh++) {
            int c = cntS[sh * N_NODES + i];
            cntS[sh * N_NODES + i] = run;
            run += c;
        }
        cnt[i] = run;
    }
    s[threadIdx.x] = run;
    __syncthreads();
    for (int off = 1; off < 256; off <<= 1) {
        int t = (threadIdx.x >= off) ? s[threadIdx.x - off] : 0;
        __syncthreads();
        s[threadIdx.x] += t;
        __syncthreads();
    }
    if (i < N_NODES) exc[i] = s[threadIdx.x] - run;
    if (threadIdx.x == 255) bsums[blockIdx.x] = s[255];
}

__global__ void k_scan2(const int* __restrict__ bsums, int* __restrict__ boffs, int nb) {
    __shared__ int s[512];
    int v = ((int)threadIdx.x < nb) ? bsums[threadIdx.x] : 0;
    s[threadIdx.x] = v;
    __syncthreads();
    for (int off = 1; off < 512; off <<= 1) {
        int t = (threadIdx.x >= off) ? s[threadIdx.x - off] : 0;
        __syncthreads();
        s[threadIdx.x] += t;
        __syncthreads();
    }
    if ((int)threadIdx.x < nb) boffs[threadIdx.x] = s[threadIdx.x] - v;
}

// scan3 + prep fused (same grid; prep is independent elementwise work)
__global__ void k_scan3(int* __restrict__ exc, const int* __restrict__ boffs,
                        const int* __restrict__ cnt, const int* __restrict__ batch,
                        float* __restrict__ invdeg, float* __restrict__ invg) {
    int i = blockIdx.x * 256 + threadIdx.x;
    if (i < N_NODES) {
        exc[i] += boffs[blockIdx.x];
        invdeg[i] = 1.0f / (float)max(cnt[i], 1);
    }
    if (i < NGRAPH) {
        int key = i, lo = 0, hi = N_NODES;
        while (lo < hi) { int m = (lo + hi) >> 1; if (batch[m] < key) lo = m + 1; else hi = m; }
        int a = lo;
        key = i + 1; lo = 0; hi = N_NODES;
        while (lo < hi) { int m = (lo + hi) >> 1; if (batch[m] < key) lo = m + 1; else hi = m; }
        invg[i] = 1.0f / (float)max(lo - a, 1);
    }
}

__global__ void k_fill(const int* __restrict__ ei, const int* __restrict__ rowptr,
                       const int* __restrict__ cntS, const int* __restrict__ rank,
                       int* __restrict__ csr) {
    int e = blockIdx.x * blockDim.x + threadIdx.x;
    if (e < N_EDGES) {
        int d = ei[N_EDGES + e];
        int s = blockIdx.x & (NSHARD - 1);
        csr[rowptr[d] + cntS[s * N_NODES + d] + rank[e]] = ei[e];
    }
}

__global__ void k_xcast(const float* __restrict__ x, ushort_t* __restrict__ xh) {
    int i = blockIdx.x * blockDim.x + threadIdx.x;
    if (i < N_NODES * 16) {
        const float4 v = ((const float4*)x)[i];
        ushort4 u;
        u.x = f2bf(v.x); u.y = f2bf(v.y); u.z = f2bf(v.z); u.w = f2bf(v.w);
        ((ushort4*)xh)[i] = u;
    }
}

// One masked group of 8 edges; bf16 rows, octet layout (q=lane>>3 edge slot,
// r=lane&7 column octet). 1 idx load + 1 dwordx4 gather per 8 edges.
__device__ __forceinline__ void grp8b(const ushort_t* __restrict__ h,
                                      const int* __restrict__ cp,
                                      int e, int deg, int q, int r,
                                      float acc[8]) {
    const int last = deg - 1;
    const int e0 = e + q;
    int i0 = cp[min(e0, last)];
    float m0 = (e0 < deg) ? 1.f : 0.f;
    const uint4 v = *(const uint4*)(h + (size_t)i0 * 64 + r * 8);
    float f[8];
    bf8_to_f32(v, f);
#pragma unroll
    for (int j = 0; j < 8; j++) acc[j] = fmaf(f[j], m0, acc[j]);
}

// ---------------- Layer pass A: gather + t-store + MFMA(W1) + BN moments ----
// r14: identical to r13 except __launch_bounds__(256, 8): LDS 17.9KB/block
// allows 8 blocks/CU (143KB of 160KB); VGPR 28 fits the 32-cap. Occupancy
// 41% -> target ~90%: doubles outstanding gathers per CU. r11's k_gq (the
// only 8-waves/EU gather we've run) ISSUED ~3.3 TB/s incl. waste — evidence
// the random-gather path has queue headroom beyond 2.75 TB/s.

__global__ __launch_bounds__(256, 8)
void k_passA(const ushort_t* __restrict__ h, const float* __restrict__ W1,
             const float* __restrict__ b1,
             const int* __restrict__ rowptr, const int* __restrict__ cnt,
             const int* __restrict__ csr, const float* __restrict__ invdeg,
             ushort_t* __restrict__ tglob, float* __restrict__ colsum,
             float* __restrict__ colsumsq) {
    __shared__ ushort_t wfrag[512 * 8];     // [(hh*4+c)*64+lane] -> 8 bf16
    __shared__ uint_t smt[4][16 * 36];      // per-wave t tile, row stride 36 dw
    __shared__ float red[128];              // block partial colsum / colsumsq

    const int w = threadIdx.x >> 6;
    const int lane = threadIdx.x & 63;
    const int q = lane >> 3;
    const int r = lane & 7;
    const int wid = __builtin_amdgcn_readfirstlane((blockIdx.x << 2) | w);
    const bool active = wid < NCHUNK;
    const int n0 = (active ? wid : 0) * AGG_CHUNK;

    // build W1 bf16 B-fragments: slot (hh,c,L): j -> W1[hh*32+(L>>4)*8+j][c*16+(L&15)]
    for (int s = threadIdx.x; s < 512; s += 256) {
        const int hh = s >> 8, c = (s >> 6) & 3, L = s & 63;
        const int kb = hh * 32 + ((L >> 4) * 8);
        const int out = c * 16 + (L & 15);
        uint_t* dst = (uint_t*)&wfrag[s * 8];
#pragma unroll
        for (int j2 = 0; j2 < 4; j2++) {
            const float lo = W1[(kb + 2 * j2) * 64 + out];
            const float hi = W1[(kb + 2 * j2 + 1) * 64 + out];
            dst[j2] = (uint_t)f2bf(lo) | ((uint_t)f2bf(hi) << 16);
        }
    }
    if (threadIdx.x < 128) red[threadIdx.x] = 0.f;
    __syncthreads();

    // gather 16 nodes (8 pairs), stage t rows as bf16 into smt
    if (active) {
        for (int pp = 0; pp < AGG_CHUNK; pp += 2) {
            const int n = n0 + pp;
            const int sa = rowptr[n],     da = cnt[n];
            const int sb = rowptr[n + 1], db = cnt[n + 1];
            const float idga = invdeg[n], idgb = invdeg[n + 1];
            const int* __restrict__ ca = csr + sa;
            const int* __restrict__ cb = csr + sb;

            float aa[8] = {0,0,0,0,0,0,0,0};
            float ab[8] = {0,0,0,0,0,0,0,0};
            const int mm = min(da, db);
            int e = 0;
            for (; e < mm; e += 8) {
                grp8b(h, ca, e, da, q, r, aa);
                grp8b(h, cb, e, db, q, r, ab);
            }
            for (; e < da; e += 8) grp8b(h, ca, e, da, q, r, aa);
            for (; e < db; e += 8) grp8b(h, cb, e, db, q, r, ab);

#pragma unroll
            for (int j = 0; j < 8; j++) {
                aa[j] += __shfl_xor(aa[j], 8, 64);
                aa[j] += __shfl_xor(aa[j], 16, 64);
                aa[j] += __shfl_xor(aa[j], 32, 64);
                ab[j] += __shfl_xor(ab[j], 8, 64);
                ab[j] += __shfl_xor(ab[j], 16, 64);
                ab[j] += __shfl_xor(ab[j], 32, 64);
            }

            const uint4 sva = *(const uint4*)(h + (size_t)n * 64 + r * 8);
            const uint4 svb = *(const uint4*)(h + (size_t)(n + 1) * 64 + r * 8);
            float sa8[8], sb8[8];
            bf8_to_f32(sva, sa8);
            bf8_to_f32(svb, sb8);
            float ta[8], tb[8];
#pragma unroll
            for (int j = 0; j < 8; j++) {
                ta[j] = fmaf(aa[j], idga, sa8[j]);
                tb[j] = fmaf(ab[j], idgb, sb8[j]);
            }

            if (q < 2) {   // lanes q==0 stage node pp, q==1 stage node pp+1
                const int row = pp + q;
                uint_t* dst = &smt[w][row * 36 + r * 4];
#pragma unroll
                for (int j2 = 0; j2 < 4; j2++) {
                    const float lo = q ? tb[2 * j2]     : ta[2 * j2];
                    const float hi = q ? tb[2 * j2 + 1] : ta[2 * j2 + 1];
                    dst[j2] = (uint_t)f2bf(lo) | ((uint_t)f2bf(hi) << 16);
                }
            }
        }
    }

    // persist t (bf16, coalesced): lane L copies 8 dwords of row L>>2
    if (active) {
        const int rr = lane >> 2, c4 = lane & 3;
        const uint_t* src = &smt[w][rr * 36 + c4 * 8];
        uintx4 v0, v1;
#pragma unroll
        for (int j = 0; j < 4; j++) { v0[j] = src[j]; v1[j] = src[4 + j]; }
        uintx4* dst = (uintx4*)((uint_t*)tglob + (size_t)(n0 + rr) * 32) + c4 * 2;
        __builtin_nontemporal_store(v0, dst);
        __builtin_nontemporal_store(v1, dst + 1);
    }

    // MFMA: A = t tile (m=lane&15, k=quad*8+j), two K-halves
    const int m = lane & 15;
    const int quad = lane >> 4;
    const short8 a0 = *(const short8*)&smt[w][m * 36 + quad * 4];
    const short8 a1 = *(const short8*)&smt[w][m * 36 + 16 + quad * 4];

    float lsum[4], lsq[4];
#pragma unroll
    for (int c = 0; c < 4; c++) {
        const short8 b0 = *(const short8*)&wfrag[(size_t)(c * 64 + lane) * 8];
        const short8 b1f = *(const short8*)&wfrag[(size_t)((4 + c) * 64 + lane) * 8];
        f32x4 D = {0.f, 0.f, 0.f, 0.f};
        D = __builtin_amdgcn_mfma_f32_16x16x32_bf16(a0, b0, D, 0, 0, 0);
        D = __builtin_amdgcn_mfma_f32_16x16x32_bf16(a1, b1f, D, 0, 0, 0);
        const float bv = b1[c * 16 + m];
        float s = 0.f, sq = 0.f;
#pragma unroll
        for (int reg = 0; reg < 4; reg++) {
            const float zv = D[reg] + bv;
            s += zv;
            sq += zv * zv;
        }
        lsum[c] = s;
        lsq[c] = sq;
    }

    if (active) {
#pragma unroll
        for (int c = 0; c < 4; c++) {
            float s = lsum[c], sq = lsq[c];
            s += __shfl_xor(s, 16, 64);
            s += __shfl_xor(s, 32, 64);
            sq += __shfl_xor(sq, 16, 64);
            sq += __shfl_xor(sq, 32, 64);
            if (quad == 0) {
                atomicAdd(&red[c * 16 + m], s);
                atomicAdd(&red[64 + c * 16 + m], sq);
            }
        }
    }
    __syncthreads();
    if (threadIdx.x < 64) {
        atomicAdd(&colsum[threadIdx.x], red[threadIdx.x]);
        atomicAdd(&colsumsq[threadIdx.x], red[64 + threadIdx.x]);
    }
}

// ---------------- Layer pass B: z=t@W1+b1 (recompute), BN+ReLU, @W2 -> h ----
// Reads t bf16 (12.8 MB vs r10's 25.6 MB z). MFMA1 reproduces passA's z
// bitwise (same bf16 fragments); BN applied in D-layout; transpose through
// wave-private ltile; MFMA2 with W2; bf16 h out.

__global__ __launch_bounds__(256, 4)
void k_passB(const ushort_t* __restrict__ t, const float* __restrict__ W1,
             const float* __restrict__ b1, const float* __restrict__ W2,
             const float* __restrict__ b2, const float* __restrict__ colsum,
             const float* __restrict__ colsumsq, const float* __restrict__ gamma,
             const float* __restrict__ beta, ushort_t* __restrict__ hout) {
    __shared__ ushort_t wf1[512 * 8];
    __shared__ ushort_t wf2[512 * 8];
    __shared__ float sscale[64], sshift[64];
    __shared__ float ltile[4][16 * 68];

    const int w = threadIdx.x >> 6;
    const int lane = threadIdx.x & 63;
    const int wid = __builtin_amdgcn_readfirstlane((blockIdx.x << 2) | w);
    const bool active = wid < NCHUNK;
    const int n0 = (active ? wid : 0) * AGG_CHUNK;

    for (int s = threadIdx.x; s < 1024; s += 256) {
        const int which = s >> 9, t2 = s & 511;
        const int hh = t2 >> 8, c = (t2 >> 6) & 3, L = t2 & 63;
        const int kb = hh * 32 + ((L >> 4) * 8);
        const int out = c * 16 + (L & 15);
        const float* W = which ? W2 : W1;
        uint_t* dst = (uint_t*)&(which ? wf2 : wf1)[t2 * 8];
#pragma unroll
        for (int j2 = 0; j2 < 4; j2++) {
            const float lo = W[(kb + 2 * j2) * 64 + out];
            const float hi = W[(kb + 2 * j2 + 1) * 64 + out];
            dst[j2] = (uint_t)f2bf(lo) | ((uint_t)f2bf(hi) << 16);
        }
    }
    if (threadIdx.x < 64) {
        const float invn = 1.0f / (float)N_NODES;
        const float mu = colsum[threadIdx.x] * invn;
        const float var = colsumsq[threadIdx.x] * invn - mu * mu;
        const float sc = gamma[threadIdx.x] * rsqrtf(var + BN_EPS);
        sscale[threadIdx.x] = sc;
        sshift[threadIdx.x] = beta[threadIdx.x] - mu * sc;
    }
    __syncthreads();

    const int m = lane & 15;
    const int quad = lane >> 4;

    // A-fragment straight from t rows (row-major bf16)
    const ushort_t* tp = t + (size_t)(n0 + m) * 64;
    const short8 a0 = __builtin_nontemporal_load((const short8*)(tp + quad * 8));
    const short8 a1 = __builtin_nontemporal_load((const short8*)(tp + 32 + quad * 8));

    // MFMA1: z tile, BN+ReLU in D-layout, stash fp32 into ltile
#pragma unroll
    for (int c = 0; c < 4; c++) {
        const short8 b0 = *(const short8*)&wf1[(size_t)(c * 64 + lane) * 8];
        const short8 b1f = *(const short8*)&wf1[(size_t)((4 + c) * 64 + lane) * 8];
        f32x4 D = {0.f, 0.f, 0.f, 0.f};
        D = __builtin_amdgcn_mfma_f32_16x16x32_bf16(a0, b0, D, 0, 0, 0);
        D = __builtin_amdgcn_mfma_f32_16x16x32_bf16(a1, b1f, D, 0, 0, 0);
        const int col = c * 16 + m;
        const float bv = b1[col];
        const float sc = sscale[col], sh = sshift[col];
#pragma unroll
        for (int reg = 0; reg < 4; reg++) {
            const float zv = D[reg] + bv;
            ltile[w][(quad * 4 + reg) * 68 + col] = fmaxf(fmaf(zv, sc, sh), 0.f);
        }
    }

    // transpose read: lane m rows, cols quad*8.. (wave-private, wave-sync)
    const float* lr = &ltile[w][m * 68];
    float r0[8], r1[8];
#pragma unroll
    for (int j = 0; j < 8; j++) {
        r0[j] = lr[quad * 8 + j];
        r1[j] = lr[32 + quad * 8 + j];
    }
    union { uint_t u[4]; short8 v; } pa0, pa1;
#pragma unroll
    for (int j2 = 0; j2 < 4; j2++) {
        pa0.u[j2] = (uint_t)f2bf(r0[2 * j2]) | ((uint_t)f2bf(r0[2 * j2 + 1]) << 16);
        pa1.u[j2] = (uint_t)f2bf(r1[2 * j2]) | ((uint_t)f2bf(r1[2 * j2 + 1]) << 16);
    }
    const short8 c0 = pa0.v;
    const short8 c1 = pa1.v;

    // MFMA2: h tile, back into ltile (all lanes re-read before overwrite:
    // wave-synchronous instruction stream makes this safe)
#pragma unroll
    for (int c = 0; c < 4; c++) {
        const short8 b0 = *(const short8*)&wf2[(size_t)(c * 64 + lane) * 8];
        const short8 b1f = *(const short8*)&wf2[(size_t)((4 + c) * 64 + lane) * 8];
        f32x4 D = {0.f, 0.f, 0.f, 0.f};
        D = __builtin_amdgcn_mfma_f32_16x16x32_bf16(c0, b0, D, 0, 0, 0);
        D = __builtin_amdgcn_mfma_f32_16x16x32_bf16(c1, b1f, D, 0, 0, 0);
        const float bv = b2[c * 16 + m];
#pragma unroll
        for (int reg = 0; reg < 4; reg++)
            ltile[w][(quad * 4 + reg) * 68 + c * 16 + m] = D[reg] + bv;
    }

    if (active) {
#pragma unroll
        for (int n = 0; n < 16; n++) {
            const float hv = ltile[w][n * 68 + lane];
            hout[(size_t)(n0 + n) * 64 + lane] = f2bf(hv);
        }
    }
}

// ---------------- Pools (deferred; linearity) -------------------------------

#define POOL_CHUNK 64

__global__ void k_pool(const ushort_t* __restrict__ h1, const ushort_t* __restrict__ h2,
                       const ushort_t* __restrict__ h3, const ushort_t* __restrict__ h4,
                       const int* __restrict__ batch, float* __restrict__ node_pool,
                       float* __restrict__ gacc) {
    const int lane = threadIdx.x & 63;
    const int wid = (blockIdx.x << 2) | (threadIdx.x >> 6);
    const int n0 = wid * POOL_CHUNK;
    if (n0 >= N_NODES) return;
    const int n1 = min(N_NODES, n0 + POOL_CHUNK);
    int curg = -1;
    float ga = 0.f;
    for (int n = n0; n < n1; n++) {
        const size_t off = (size_t)n * 64 + lane;
        const float v = bf2f(h1[off]) + bf2f(h2[off]) + bf2f(h3[off]) + bf2f(h4[off]);
        __builtin_nontemporal_store(v, &node_pool[off]);
        const int g = batch[n];
        if (g != curg) {
            if (curg >= 0) atomicAdd(&gacc[curg * 64 + lane], ga);
            ga = 0.f;
            curg = g;
        }
        ga += v;
    }
    if (curg >= 0) atomicAdd(&gacc[curg * 64 + lane], ga);
}

__global__ void k_gfinal(const float* __restrict__ gacc, const float* __restrict__ invg,
                         float* __restrict__ gout) {
    int i = blockIdx.x * blockDim.x + threadIdx.x;
    if (i < NGRAPH * 64) gout[i] = gacc[i] * invg[i >> 6];
}

// ---------------- launch ----------------

extern "C" void kernel_launch(void* const* d_in, const int* in_sizes, int n_in,
                              void* d_out, int out_size, void* d_ws, size_t ws_size,
                              hipStream_t stream) {
    (void)in_sizes; (void)n_in; (void)out_size; (void)ws_size;
    const float* x     = (const float*)d_in[0];
    const int*   ei    = (const int*)d_in[1];
    const int*   batch = (const int*)d_in[2];
    const float* W1    = (const float*)d_in[3];
    const float* b1    = (const float*)d_in[4];
    const float* gamma = (const float*)d_in[5];
    const float* beta  = (const float*)d_in[6];
    const float* W2    = (const float*)d_in[7];
    const float* b2    = (const float*)d_in[8];
    float* out = (float*)d_out;  // [N*64] node_pool, then [G*64] g_pool

    // element offsets (4B units)
    size_t o = 0;
    size_t o_cntS    = o; o += (size_t)NSHARD * N_NODES;
    size_t o_colsum  = o; o += (size_t)NLAYER * 64;
    size_t o_colsq   = o; o += (size_t)NLAYER * 64;
    size_t o_gacc    = o; o += (size_t)NGRAPH * 64;
    size_t zero_elems = o;
    size_t o_cnt     = o; o += N_NODES;
    size_t o_rowptr  = o; o += N_NODES;
    size_t o_bsums   = o; o += 512;
    size_t o_boffs   = o; o += 512;
    size_t o_invdeg  = o; o += N_NODES;
    size_t o_invg    = o; o += NGRAPH;
    size_t o_rank    = o; o += N_EDGES;
    size_t o_csr     = o; o += N_EDGES;
    size_t o_t       = o; o += (size_t)N_NODES * 32;   // t, bf16 (N*64 ushorts)
    size_t o_h0      = o; o += (size_t)N_NODES * 32;   // per-layer h, bf16
    size_t o_h1      = o; o += (size_t)N_NODES * 32;
    size_t o_h2      = o; o += (size_t)N_NODES * 32;
    size_t o_xh      = o; o += (size_t)N_NODES * 32;   // x bf16; reused as h4

    int*   wsi = (int*)d_ws;
    float* wsf = (float*)d_ws;
    int*      cntS   = wsi + o_cntS;
    float*    colsum = wsf + o_colsum;
    float*    colsq  = wsf + o_colsq;
    float*    gacc   = wsf + o_gacc;
    int*      cnt    = wsi + o_cnt;
    int*      rowptr = wsi + o_rowptr;
    int*      bsums  = wsi + o_bsums;
    int*      boffs  = wsi + o_boffs;
    float*    invdeg = wsf + o_invdeg;
    float*    invg   = wsf + o_invg;
    int*      rank   = wsi + o_rank;
    int*      csr    = wsi + o_csr;
    ushort_t* tbuf   = (ushort_t*)(wsi + o_t);
    ushort_t* hb0    = (ushort_t*)(wsi + o_h0);
    ushort_t* hb1    = (ushort_t*)(wsi + o_h1);
    ushort_t* hb2    = (ushort_t*)(wsi + o_h2);
    ushort_t* xh     = (ushort_t*)(wsi + o_xh);   // layer-0 input; layer-3 output

    hipMemsetAsync(d_ws, 0, zero_elems * 4, stream);

    const int eb = (N_EDGES + 255) / 256;
    const int nb = (N_NODES + 255) / 256;  // 391 <= 512

    k_hist<<<eb, 256, 0, stream>>>(ei, cntS, rank);
    k_xcast<<<(N_NODES * 16 + 255) / 256, 256, 0, stream>>>(x, xh);
    k_sumscan<<<nb, 256, 0, stream>>>(cntS, cnt, rowptr, bsums);
    k_scan2<<<1, 512, 0, stream>>>(bsums, boffs, nb);
    k_scan3<<<nb, 256, 0, stream>>>(rowptr, boffs, cnt, batch, invdeg, invg);
    k_fill<<<eb, 256, 0, stream>>>(ei, rowptr, cntS, rank, csr);

    const ushort_t* hin[NLAYER]  = {xh,  hb0, hb1, hb2};
    ushort_t*       hoz[NLAYER]  = {hb0, hb1, hb2, xh};   // layer-3 out aliases xh

    const int gridA = (NCHUNK + 3) / 4;  // 1563
    for (int l = 0; l < NLAYER; l++) {
        k_passA<<<gridA, 256, 0, stream>>>(hin[l], W1 + l * 4096, b1 + l * 64,
                                           rowptr, cnt, csr, invdeg,
                                           tbuf, colsum + l * 64, colsq + l * 64);
        k_passB<<<gridA, 256, 0, stream>>>(tbuf, W1 + l * 4096, b1 + l * 64,
                                           W2 + l * 4096, b2 + l * 64,
                                           colsum + l * 64, colsq + l * 64,
                                           gamma + l * 64, beta + l * 64, hoz[l]);
    }
    const int gridP = (N_NODES + POOL_CHUNK * 4 - 1) / (POOL_CHUNK * 4);
    k_pool<<<gridP, 256, 0, stream>>>(hb0, hb1, hb2, xh, batch, out, gacc);
    k_gfinal<<<32, 256, 0, stream>>>(gacc, invg, out + (size_t)N_NODES * 64);
}